// Round 1
// baseline (1427.029 us; speedup 1.0000x reference)
//
#include <hip/hip_runtime.h>

// Problem constants
#define Bn 3
#define GSn 8
#define Un 100000
#define Gn 4096
#define Hn 128
#define Mn 80000
#define NHID 2048              // G/2

#define N_ONES 338304          // B*GS*G (98304) + B*M (240000)
#define OUT_W_OFF 338304       // start of weights output [B,GS,1]

// workspace layout (floats)
#define TE_OFF 0               // tempembed [GS*G] = 32768
#define TEMLAT_OFF 32768       // temlat accumulators [8*2048] = 16384

// ---------------------------------------------------------------------------
// 1) Fill outputs 1 & 2 with ones (softmax-sum identity), zero temlat accum.
__global__ void fill_kernel(float* __restrict__ out, float* __restrict__ temlat) {
    int i = blockIdx.x * 256 + threadIdx.x;
    if (i < N_ONES / 4) {
        reinterpret_cast<float4*>(out)[i] = make_float4(1.f, 1.f, 1.f, 1.f);
    } else {
        int j = i - N_ONES / 4;
        if (j < (8 * NHID) / 4)
            reinterpret_cast<float4*>(temlat)[j] = make_float4(0.f, 0.f, 0.f, 0.f);
    }
}

// ---------------------------------------------------------------------------
// 2) tempembed[s,g] = mean_h user_embedding_gk[2, s, idx[s,g], h]
//    one 64-lane wave per (s,g) row; lane loads float2, shuffle-reduce.
__global__ void gather_mean(const float* __restrict__ gk,
                            const int* __restrict__ idx,
                            float* __restrict__ te) {
    int row = blockIdx.x * 4 + (threadIdx.x >> 6);   // 4 waves / block
    int lane = threadIdx.x & 63;
    int s = row >> 12;            // / 4096
    int u = idx[row];             // user_id_groups[s,g], row-major
    const float* p = gk + ((long long)((2 * GSn + s) * (long long)Un + u)) * Hn;
    float2 v = *reinterpret_cast<const float2*>(p + lane * 2);
    float sum = v.x + v.y;
    #pragma unroll
    for (int off = 32; off; off >>= 1) sum += __shfl_down(sum, off);
    if (lane == 0) te[row] = sum * (1.0f / 128.0f);
}

// ---------------------------------------------------------------------------
// 3) temlat[s,n] += sum_k te[s,k] * fc1_W[k,n]   (k-split x64, atomic combine)
//    grid = 8 n-blocks x 64 k-blocks; thread n-column, coalesced W reads.
__global__ void fc1_kernel(const float* __restrict__ te,
                           const float* __restrict__ W,
                           float* __restrict__ temlat) {
    __shared__ float lte[8][64];
    int nblk = blockIdx.x & 7;
    int kblk = blockIdx.x >> 3;
    int tid = threadIdx.x;
    int k0 = kblk * 64;
    for (int i = tid; i < 8 * 64; i += 256) {
        int s = i >> 6, k = i & 63;
        lte[s][k] = te[s * Gn + k0 + k];
    }
    __syncthreads();
    int n = nblk * 256 + tid;
    float acc[8] = {0.f, 0.f, 0.f, 0.f, 0.f, 0.f, 0.f, 0.f};
    for (int kk = 0; kk < 64; kk++) {
        float wv = W[(size_t)(k0 + kk) * NHID + n];
        #pragma unroll
        for (int s = 0; s < 8; s++) acc[s] += lte[s][kk] * wv;
    }
    #pragma unroll
    for (int s = 0; s < 8; s++) atomicAdd(&temlat[s * NHID + n], acc[s]);
}

// ---------------------------------------------------------------------------
// 4) w[s] = sum_n relu(temlat[s,n] + fc1_b[n]) * fc2_W[n] + fc2_b
//    single block, tree reduce; broadcast to [B,GS,1].
__global__ void fc2_kernel(const float* __restrict__ temlat,
                           const float* __restrict__ fc1b,
                           const float* __restrict__ fc2w,
                           const float* __restrict__ fc2b,
                           float* __restrict__ out) {
    int t = threadIdx.x;
    float acc[8] = {0.f, 0.f, 0.f, 0.f, 0.f, 0.f, 0.f, 0.f};
    for (int n = t; n < NHID; n += 256) {
        float b1 = fc1b[n];
        float w2 = fc2w[n];
        #pragma unroll
        for (int s = 0; s < 8; s++) {
            float v = temlat[s * NHID + n] + b1;
            v = v > 0.f ? v : 0.f;
            acc[s] += v * w2;
        }
    }
    __shared__ float red[8][256];
    #pragma unroll
    for (int s = 0; s < 8; s++) red[s][t] = acc[s];
    __syncthreads();
    for (int off = 128; off; off >>= 1) {
        if (t < off) {
            #pragma unroll
            for (int s = 0; s < 8; s++) red[s][t] += red[s][t + off];
        }
        __syncthreads();
    }
    if (t < 8) {
        float w = red[t][0] + fc2b[0];
        out[OUT_W_OFF + 0 * GSn + t] = w;
        out[OUT_W_OFF + 1 * GSn + t] = w;
        out[OUT_W_OFF + 2 * GSn + t] = w;
    }
}

// ---------------------------------------------------------------------------
extern "C" void kernel_launch(void* const* d_in, const int* in_sizes, int n_in,
                              void* d_out, int out_size, void* d_ws, size_t ws_size,
                              hipStream_t stream) {
    // setup_inputs() dict order:
    //  0 user_embeddings [B,U,H]          1 user_embedding_gk [B,GS,U,H]
    //  2 infoNCELoss_group_list           3 behavior_loss_list
    //  4 user_id_groups [GS,G] int32      5 user_index_list [B,M] int32
    //  6 mn1_W 7 mn1_b
    //  8..12  mlp0 (pW,pB,a,oW,oB)       13..17 mlp1
    // 18 mn2_W 19 mn2_b
    // 20..24 mlp2                        25..29 mlp3
    // 30 fc1_W [4096,2048] 31 fc1_b [2048] 32 fc2_W [2048,1] 33 fc2_b [1]
    const float* gk    = (const float*)d_in[1];
    const int*   idx   = (const int*)d_in[4];
    const float* fc1W  = (const float*)d_in[30];
    const float* fc1b  = (const float*)d_in[31];
    const float* fc2w  = (const float*)d_in[32];
    const float* fc2b  = (const float*)d_in[33];
    float* out = (float*)d_out;
    float* ws  = (float*)d_ws;

    float* te     = ws + TE_OFF;       // [GS*G]
    float* temlat = ws + TEMLAT_OFF;   // [8*NHID] accumulators

    // 1) ones + zero accumulators: (338304/4 + 16384/4) threads
    {
        int nthreads = N_ONES / 4 + (8 * NHID) / 4;
        int blocks = (nthreads + 255) / 256;
        fill_kernel<<<blocks, 256, 0, stream>>>(out, temlat);
    }
    // 2) gather + mean over H: 32768 rows, 4 waves/block
    gather_mean<<<(GSn * Gn) / 4, 256, 0, stream>>>(gk, idx, te);
    // 3) fc1 partial GEMM: 8 n-blocks x 64 k-blocks
    fc1_kernel<<<8 * 64, 256, 0, stream>>>(te, fc1W, temlat);
    // 4) fc2 reduction + broadcast
    fc2_kernel<<<1, 256, 0, stream>>>(temlat, fc1b, fc2w, fc2b, out);
}